// Round 1
// baseline (923.777 us; speedup 1.0000x reference)
//
#include <hip/hip_runtime.h>

#define VV 10000
#define EE 128
#define NROWS 2048   // B*C = 16*128
#define NREL 8

// ---------------------------------------------------------------------------
// K1: base[n][v] = dot(SE[n][:], W[v][:])   (NT gemm, K=128 contiguous both)
// grid (157 v-tiles, 32 n-tiles), block 256. Tile 64x64, 4x4 micro per thread.
// ---------------------------------------------------------------------------
__global__ __launch_bounds__(256) void k1_base_gemm(
    const float* __restrict__ SE,   // [2048][128]
    const float* __restrict__ W,    // [10000][128]
    float* __restrict__ base)       // [2048][10000]
{
    __shared__ float As[32 * 64];   // As[k][n]
    __shared__ float Ws[32 * 64];   // Ws[k][v]
    const int tid = threadIdx.x;
    const int v0 = blockIdx.x * 64;
    const int n0 = blockIdx.y * 64;
    const int tx = tid & 15;        // v micro group  (cols tx*4..+3)
    const int ty = tid >> 4;        // n micro group  (rows ty*4..+3)

    float acc[4][4];
    #pragma unroll
    for (int i = 0; i < 4; i++)
        #pragma unroll
        for (int j = 0; j < 4; j++) acc[i][j] = 0.f;

    for (int e0 = 0; e0 < EE; e0 += 32) {
        #pragma unroll
        for (int p = 0; p < 2; p++) {
            int f = tid + p * 256;      // 0..511 float4 slots
            int row = f >> 3;           // 0..63
            int c4  = f & 7;            // 0..7 -> k = c4*4
            float4 a = *(const float4*)(SE + (n0 + row) * EE + e0 + c4 * 4);
            As[(c4 * 4 + 0) * 64 + row] = a.x;
            As[(c4 * 4 + 1) * 64 + row] = a.y;
            As[(c4 * 4 + 2) * 64 + row] = a.z;
            As[(c4 * 4 + 3) * 64 + row] = a.w;
            int vrow = v0 + row;
            float4 b;
            if (vrow < VV) b = *(const float4*)(W + vrow * EE + e0 + c4 * 4);
            else           b = make_float4(0.f, 0.f, 0.f, 0.f);
            Ws[(c4 * 4 + 0) * 64 + row] = b.x;
            Ws[(c4 * 4 + 1) * 64 + row] = b.y;
            Ws[(c4 * 4 + 2) * 64 + row] = b.z;
            Ws[(c4 * 4 + 3) * 64 + row] = b.w;
        }
        __syncthreads();
        #pragma unroll
        for (int kk = 0; kk < 32; kk++) {
            float4 a4 = *(const float4*)(As + kk * 64 + ty * 4);
            float4 b4 = *(const float4*)(Ws + kk * 64 + tx * 4);
            float av[4] = {a4.x, a4.y, a4.z, a4.w};
            float bv[4] = {b4.x, b4.y, b4.z, b4.w};
            #pragma unroll
            for (int i = 0; i < 4; i++)
                #pragma unroll
                for (int j = 0; j < 4; j++)
                    acc[i][j] = fmaf(av[i], bv[j], acc[i][j]);
        }
        __syncthreads();
    }

    #pragma unroll
    for (int i = 0; i < 4; i++) {
        int n = n0 + ty * 4 + i;
        #pragma unroll
        for (int j = 0; j < 4; j++) {
            int v = v0 + tx * 4 + j;
            if (v < VV) base[(long long)n * VV + v] = acc[i][j];
        }
    }
}

// ---------------------------------------------------------------------------
// K2: per row n: gather rel/edge rows, compute per-relation softmax stats,
// relation-weight softmax, and rewrite base row in place as the combined
// attention coefficient row A[v].  grid 2048, block 256.
// accv layout: 0 sumbase; 1+q cnt_q; 9+q B_q; 17+q P_q(=sum exp b); 25+q PB_q
// ---------------------------------------------------------------------------
__global__ __launch_bounds__(256) void k2_stats(
    const int*   __restrict__ src,     // [2048]
    const float* __restrict__ edge,    // [V][V]
    const int*   __restrict__ rel,     // [V][V]
    float* __restrict__ baseA)         // [2048][10000] in/out
{
    __shared__ float sb[VV];
    __shared__ unsigned char srb[VV];
    __shared__ float wred[33][4];
    __shared__ float fin[33];
    __shared__ float bcast[12];

    const int n = blockIdx.x;
    const int tid = threadIdx.x;
    const int lane = tid & 63;
    const int wv = tid >> 6;
    const long long srow = (long long)src[n] * VV;
    float* brow = baseA + (long long)n * VV;

    float accv[33];
    #pragma unroll
    for (int i = 0; i < 33; i++) accv[i] = 0.f;

    for (int v = tid; v < VV; v += 256) {
        float b = brow[v];
        int   r = rel[srow + v];
        float e = edge[srow + v];
        int  rb = (r > 0 && r <= 8 && e > 0.f) ? r : 0;
        sb[v] = b;
        srb[v] = (unsigned char)rb;
        float eb  = __expf(b);
        float beb = b * eb;
        accv[0] += b;
        #pragma unroll
        for (int q = 0; q < 8; q++) {
            float s = (rb == q + 1) ? 1.f : 0.f;
            accv[1 + q]  += s;
            accv[9 + q]  = fmaf(s, b,   accv[9 + q]);
            accv[17 + q] = fmaf(s, eb,  accv[17 + q]);
            accv[25 + q] = fmaf(s, beb, accv[25 + q]);
        }
    }

    #pragma unroll
    for (int i = 0; i < 33; i++) {
        float x = accv[i];
        #pragma unroll
        for (int off = 32; off > 0; off >>= 1) x += __shfl_xor(x, off, 64);
        if (lane == 0) wred[i][wv] = x;
    }
    __syncthreads();
    if (tid < 33)
        fin[tid] = wred[tid][0] + wred[tid][1] + wred[tid][2] + wred[tid][3];
    __syncthreads();

    if (tid == 0) {
        float sumbase = fin[0];
        float s[8], Z[8];
        float smax = -1e30f;
        #pragma unroll
        for (int q = 0; q < 8; q++) {
            float cnt = fin[1 + q], Bq = fin[9 + q];
            float Pq  = fin[17 + q], PBq = fin[25 + q];
            Z[q] = ((float)VV - cnt) + Pq;                 // sum of exp(cw), m=0
            s[q] = (sumbase - Bq + PBq) / Z[q];            // attn . base
            smax = fmaxf(smax, s[q]);
        }
        float wsum = 0.f, wq[8];
        #pragma unroll
        for (int q = 0; q < 8; q++) { wq[q] = __expf(s[q] - smax); wsum += wq[q]; }
        float Kc = 0.f;
        #pragma unroll
        for (int q = 0; q < 8; q++) {
            float c = (wq[q] / wsum) / Z[q];
            bcast[1 + q] = c;
            Kc += c;
        }
        bcast[0] = Kc;
    }
    __syncthreads();

    const float Kc = bcast[0];
    float cf[8];
    #pragma unroll
    for (int q = 0; q < 8; q++) cf[q] = bcast[1 + q];

    for (int v = tid; v < VV; v += 256) {
        float b = sb[v];
        int rb = srb[v];
        float cc = 0.f;
        #pragma unroll
        for (int q = 0; q < 8; q++) cc += (rb == q + 1) ? cf[q] : 0.f;
        brow[v] = fmaf(cc, __expf(b) - 1.f, Kc);   // rb==0 -> cc==0 -> Kc
    }
}

// ---------------------------------------------------------------------------
// K3: out[n][e] = sum_v A[n][v] * W[v][e].  M-tile 32, split-K 8, atomicAdd.
// grid (64 m-tiles, 8 k-splits), block 256. 4x4 micro per thread.
// ---------------------------------------------------------------------------
__global__ __launch_bounds__(256) void k3_out_gemm(
    const float* __restrict__ A,    // [2048][10000]
    const float* __restrict__ W,    // [10000][128]
    float* __restrict__ out)        // [2048][128] (pre-zeroed)
{
    __shared__ float As[32 * 32];    // As[k][n], stride 32
    __shared__ float Ws[32 * 132];   // Ws[k][e], stride 132 (pad)
    const int tid = threadIdx.x;
    const int m0 = blockIdx.x * 32;
    const int ks = blockIdx.y;       // 0..7
    const int tx = tid & 31;         // col group e = tx*4..+3
    const int ty = tid >> 5;         // row group n = ty*4..+3

    float acc[4][4];
    #pragma unroll
    for (int i = 0; i < 4; i++)
        #pragma unroll
        for (int j = 0; j < 4; j++) acc[i][j] = 0.f;

    for (int kt = ks; kt < 313; kt += 8) {
        int k0 = kt * 32;
        {   // A chunk: 32n x 32k
            int row = tid >> 3;      // n local
            int c4  = tid & 7;       // k group
            int k = k0 + c4 * 4;
            const float* ap = A + (long long)(m0 + row) * VV;
            float4 a;
            if (k + 3 < VV) a = *(const float4*)(ap + k);
            else {
                a.x = (k + 0 < VV) ? ap[k + 0] : 0.f;
                a.y = (k + 1 < VV) ? ap[k + 1] : 0.f;
                a.z = (k + 2 < VV) ? ap[k + 2] : 0.f;
                a.w = (k + 3 < VV) ? ap[k + 3] : 0.f;
            }
            As[(c4 * 4 + 0) * 32 + row] = a.x;
            As[(c4 * 4 + 1) * 32 + row] = a.y;
            As[(c4 * 4 + 2) * 32 + row] = a.z;
            As[(c4 * 4 + 3) * 32 + row] = a.w;
        }
        #pragma unroll
        for (int p = 0; p < 4; p++) {   // W chunk: 32k x 128e
            int f = tid + p * 256;
            int row = f >> 5;           // k local
            int c4  = f & 31;           // e group
            int k = k0 + row;
            float4 w4 = (k < VV) ? *(const float4*)(W + (long long)k * EE + c4 * 4)
                                 : make_float4(0.f, 0.f, 0.f, 0.f);
            *(float4*)(Ws + row * 132 + c4 * 4) = w4;
        }
        __syncthreads();
        #pragma unroll
        for (int kk = 0; kk < 32; kk++) {
            float4 a4 = *(const float4*)(As + kk * 32 + ty * 4);
            float4 w4 = *(const float4*)(Ws + kk * 132 + tx * 4);
            float av[4] = {a4.x, a4.y, a4.z, a4.w};
            float wv[4] = {w4.x, w4.y, w4.z, w4.w};
            #pragma unroll
            for (int i = 0; i < 4; i++)
                #pragma unroll
                for (int j = 0; j < 4; j++)
                    acc[i][j] = fmaf(av[i], wv[j], acc[i][j]);
        }
        __syncthreads();
    }

    #pragma unroll
    for (int i = 0; i < 4; i++) {
        int mrow = m0 + ty * 4 + i;
        #pragma unroll
        for (int j = 0; j < 4; j++)
            atomicAdd(out + mrow * EE + tx * 4 + j, acc[i][j]);
    }
}

extern "C" void kernel_launch(void* const* d_in, const int* in_sizes, int n_in,
                              void* d_out, int out_size, void* d_ws, size_t ws_size,
                              hipStream_t stream) {
    const int*   src  = (const int*)  d_in[0];   // [16][128]
    const float* SE   = (const float*)d_in[1];   // [16][128][128]
    const float* W    = (const float*)d_in[2];   // [10000][128]
    const float* edge = (const float*)d_in[3];   // [10000][10000]
    const int*   rel  = (const int*)  d_in[4];   // [10000][10000]
    float* out  = (float*)d_out;                 // [16][128][128]
    float* base = (float*)d_ws;                  // [2048][10000] fp32 = 78.1 MiB

    hipMemsetAsync(d_out, 0, (size_t)out_size * sizeof(float), stream);
    k1_base_gemm<<<dim3(157, 32), 256, 0, stream>>>(SE, W, base);
    k2_stats<<<dim3(NROWS), 256, 0, stream>>>(src, edge, rel, base);
    k3_out_gemm<<<dim3(64, 8), 256, 0, stream>>>(base, W, out);
}

// Round 2
// 810.844 us; speedup vs baseline: 1.1393x; 1.1393x over previous
//
#include <hip/hip_runtime.h>

#define VV 10000
#define EE 128
#define NROWS 2048   // B*C
#define NSPLIT 16    // K3 split-K factor

// ---------------------------------------------------------------------------
// K1: base[n][v] = dot(SE[n][:], W[v][:])  (NT, K=128)
// 128x128 tile, BK=32, 256 threads, 8x8 micro => 1 B LDS per FMA (VALU-bound).
// grid (79 v-tiles, 16 n-tiles).
// ---------------------------------------------------------------------------
__global__ __launch_bounds__(256) void k1_base_gemm(
    const float* __restrict__ SE,   // [2048][128]
    const float* __restrict__ W,    // [10000][128]
    float* __restrict__ base)       // [2048][10000]
{
    __shared__ float As[32 * 132];  // [k][n], pad 128->132 (write-conflict relief)
    __shared__ float Ws[32 * 132];  // [k][v]
    const int tid = threadIdx.x;
    const int v0 = blockIdx.x * 128;
    const int n0 = blockIdx.y * 128;
    const int tx = tid & 15;        // v cols tx*8..+7
    const int ty = tid >> 4;        // n rows ty*8..+7

    float acc[8][8];
    #pragma unroll
    for (int i = 0; i < 8; i++)
        #pragma unroll
        for (int j = 0; j < 8; j++) acc[i][j] = 0.f;

    for (int e0 = 0; e0 < EE; e0 += 32) {
        #pragma unroll
        for (int p = 0; p < 4; p++) {
            int f = tid + p * 256;      // 0..1023 float4 slots
            int row = f >> 3;           // 0..127
            int c4  = f & 7;            // k group, k = c4*4
            float4 a = *(const float4*)(SE + (n0 + row) * EE + e0 + c4 * 4);
            As[(c4 * 4 + 0) * 132 + row] = a.x;
            As[(c4 * 4 + 1) * 132 + row] = a.y;
            As[(c4 * 4 + 2) * 132 + row] = a.z;
            As[(c4 * 4 + 3) * 132 + row] = a.w;
            int vrow = v0 + row;
            float4 b = (vrow < VV) ? *(const float4*)(W + vrow * EE + e0 + c4 * 4)
                                   : make_float4(0.f, 0.f, 0.f, 0.f);
            Ws[(c4 * 4 + 0) * 132 + row] = b.x;
            Ws[(c4 * 4 + 1) * 132 + row] = b.y;
            Ws[(c4 * 4 + 2) * 132 + row] = b.z;
            Ws[(c4 * 4 + 3) * 132 + row] = b.w;
        }
        __syncthreads();
        #pragma unroll 4
        for (int kk = 0; kk < 32; kk++) {
            float4 a0 = *(const float4*)(As + kk * 132 + ty * 8);
            float4 a1 = *(const float4*)(As + kk * 132 + ty * 8 + 4);
            float4 b0 = *(const float4*)(Ws + kk * 132 + tx * 8);
            float4 b1 = *(const float4*)(Ws + kk * 132 + tx * 8 + 4);
            float av[8] = {a0.x, a0.y, a0.z, a0.w, a1.x, a1.y, a1.z, a1.w};
            float bv[8] = {b0.x, b0.y, b0.z, b0.w, b1.x, b1.y, b1.z, b1.w};
            #pragma unroll
            for (int i = 0; i < 8; i++)
                #pragma unroll
                for (int j = 0; j < 8; j++)
                    acc[i][j] = fmaf(av[i], bv[j], acc[i][j]);
        }
        __syncthreads();
    }

    #pragma unroll
    for (int i = 0; i < 8; i++) {
        int n = n0 + ty * 8 + i;
        float* brow = base + (long long)n * VV;
        #pragma unroll
        for (int jj = 0; jj < 2; jj++) {
            int v = v0 + tx * 8 + jj * 4;   // VV%4==0 -> all-in or all-out
            if (v < VV)
                *(float4*)(brow + v) = make_float4(acc[i][jj * 4 + 0], acc[i][jj * 4 + 1],
                                                   acc[i][jj * 4 + 2], acc[i][jj * 4 + 3]);
        }
    }
}

// ---------------------------------------------------------------------------
// K2: per row n: vectorized gather of rel/edge rows + base row, per-relation
// softmax stats, relation softmax, rewrite base row in place as A[v].
// accv: 0 sumbase; 1+q cnt; 9+q B_q; 17+q P_q; 25+q PB_q.   grid 2048.
// ---------------------------------------------------------------------------
__global__ __launch_bounds__(256) void k2_stats(
    const int*   __restrict__ src,
    const float* __restrict__ edge,    // [V][V]
    const int*   __restrict__ rel,     // [V][V]
    float* __restrict__ baseA)         // [2048][10000] in/out
{
    __shared__ float seb[VV];              // exp(base)
    __shared__ unsigned char srb[VV];      // relation code 0..8
    __shared__ float wred[33][4];
    __shared__ float fin[33];
    __shared__ float cvals[12];            // [0]=0, [1..8]=c_q, [9]=Kc

    const int n = blockIdx.x;
    const int tid = threadIdx.x;
    const int lane = tid & 63;
    const int wv = tid >> 6;
    const int s = src[n];
    const float4* brow4 = (const float4*)(baseA + (long long)n * VV);
    const float4* erow4 = (const float4*)(edge + (long long)s * VV);
    const int4*   rrow4 = (const int4*)(rel + (long long)s * VV);

    float accv[33];
    #pragma unroll
    for (int i = 0; i < 33; i++) accv[i] = 0.f;

    for (int v4 = tid; v4 < VV / 4; v4 += 256) {
        float4 b = brow4[v4];
        float4 e = erow4[v4];
        int4   r = rrow4[v4];
        float bb[4] = {b.x, b.y, b.z, b.w};
        float ee[4] = {e.x, e.y, e.z, e.w};
        int   rr[4] = {r.x, r.y, r.z, r.w};
        #pragma unroll
        for (int c = 0; c < 4; c++) {
            int rb = (rr[c] >= 1 && rr[c] <= 8 && ee[c] > 0.f) ? rr[c] : 0;
            float bc = bb[c];
            float eb = __expf(bc);
            float beb = bc * eb;
            seb[v4 * 4 + c] = eb;
            srb[v4 * 4 + c] = (unsigned char)rb;
            accv[0] += bc;
            #pragma unroll
            for (int q = 0; q < 8; q++) {
                float m = (rb == q + 1) ? 1.f : 0.f;
                accv[1 + q]  += m;
                accv[9 + q]  = fmaf(m, bc,  accv[9 + q]);
                accv[17 + q] = fmaf(m, eb,  accv[17 + q]);
                accv[25 + q] = fmaf(m, beb, accv[25 + q]);
            }
        }
    }

    #pragma unroll
    for (int i = 0; i < 33; i++) {
        float x = accv[i];
        #pragma unroll
        for (int off = 32; off > 0; off >>= 1) x += __shfl_xor(x, off, 64);
        if (lane == 0) wred[i][wv] = x;
    }
    __syncthreads();
    if (tid < 33)
        fin[tid] = wred[tid][0] + wred[tid][1] + wred[tid][2] + wred[tid][3];
    __syncthreads();

    if (tid == 0) {
        float sumbase = fin[0];
        float sc[8], Z[8];
        float smax = -1e30f;
        #pragma unroll
        for (int q = 0; q < 8; q++) {
            Z[q]  = ((float)VV - fin[1 + q]) + fin[17 + q];
            sc[q] = (sumbase - fin[9 + q] + fin[25 + q]) / Z[q];
            smax = fmaxf(smax, sc[q]);
        }
        float wsum = 0.f, wq[8];
        #pragma unroll
        for (int q = 0; q < 8; q++) { wq[q] = __expf(sc[q] - smax); wsum += wq[q]; }
        float Kc = 0.f;
        #pragma unroll
        for (int q = 0; q < 8; q++) {
            float c = (wq[q] / wsum) / Z[q];
            cvals[1 + q] = c;
            Kc += c;
        }
        cvals[0] = 0.f;
        cvals[9] = Kc;
    }
    __syncthreads();

    const float Kc = cvals[9];
    float4* broww = (float4*)(baseA + (long long)n * VV);
    for (int v4 = tid; v4 < VV / 4; v4 += 256) {
        float o[4];
        #pragma unroll
        for (int c = 0; c < 4; c++) {
            float eb = seb[v4 * 4 + c];
            float cc = cvals[srb[v4 * 4 + c]];        // 0 for unmasked
            o[c] = fmaf(cc, eb - 1.f, Kc);
        }
        broww[v4] = make_float4(o[0], o[1], o[2], o[3]);
    }
}

// ---------------------------------------------------------------------------
// K3: partial[ks][n][e] = sum_{k in split ks} A[n][k] * W[k][e]
// 64x128 tile, BK=32, split-K 16 round-robin, 4x8 micro, no atomics.
// grid (32 m-tiles, 16 splits) = 512 blocks.
// ---------------------------------------------------------------------------
__global__ __launch_bounds__(256) void k3_gemm(
    const float* __restrict__ A,    // [2048][10000]
    const float* __restrict__ W,    // [10000][128]
    float* __restrict__ part)       // [16][2048][128]
{
    __shared__ float As[32 * 68];    // [k][m], pad 64->68
    __shared__ float Ws[32 * 132];   // [k][e], pad 128->132
    const int tid = threadIdx.x;
    const int m0 = blockIdx.x * 64;
    const int ks = blockIdx.y;
    const int tx = tid & 15;         // e cols tx*8..+7
    const int ty = tid >> 4;         // m rows ty*4..+3

    float acc[4][8];
    #pragma unroll
    for (int i = 0; i < 4; i++)
        #pragma unroll
        for (int j = 0; j < 8; j++) acc[i][j] = 0.f;

    for (int kt = ks; kt < 313; kt += NSPLIT) {
        int k0 = kt * 32;
        #pragma unroll
        for (int p = 0; p < 2; p++) {    // A: 64m x 32k
            int f = tid + p * 256;
            int row = f >> 3;            // 0..63
            int c4  = f & 7;
            int k = k0 + c4 * 4;         // mult of 4; VV%4==0
            float4 a = (k < VV) ? *(const float4*)(A + (long long)(m0 + row) * VV + k)
                                : make_float4(0.f, 0.f, 0.f, 0.f);
            As[(c4 * 4 + 0) * 68 + row] = a.x;
            As[(c4 * 4 + 1) * 68 + row] = a.y;
            As[(c4 * 4 + 2) * 68 + row] = a.z;
            As[(c4 * 4 + 3) * 68 + row] = a.w;
        }
        #pragma unroll
        for (int p = 0; p < 4; p++) {    // W: 32k x 128e (b128 LDS writes)
            int f = tid + p * 256;
            int krow = f >> 5;           // 0..31
            int c4   = f & 31;
            int k = k0 + krow;
            float4 w4 = (k < VV) ? *(const float4*)(W + (long long)k * EE + c4 * 4)
                                 : make_float4(0.f, 0.f, 0.f, 0.f);
            *(float4*)(Ws + krow * 132 + c4 * 4) = w4;
        }
        __syncthreads();
        #pragma unroll 4
        for (int kk = 0; kk < 32; kk++) {
            float4 a4 = *(const float4*)(As + kk * 68 + ty * 4);
            float4 b0 = *(const float4*)(Ws + kk * 132 + tx * 8);
            float4 b1 = *(const float4*)(Ws + kk * 132 + tx * 8 + 4);
            float av[4] = {a4.x, a4.y, a4.z, a4.w};
            float bv[8] = {b0.x, b0.y, b0.z, b0.w, b1.x, b1.y, b1.z, b1.w};
            #pragma unroll
            for (int i = 0; i < 4; i++)
                #pragma unroll
                for (int j = 0; j < 8; j++)
                    acc[i][j] = fmaf(av[i], bv[j], acc[i][j]);
        }
        __syncthreads();
    }

    float* pp = part + (long long)ks * NROWS * EE;
    #pragma unroll
    for (int i = 0; i < 4; i++) {
        int m = m0 + ty * 4 + i;
        *(float4*)(pp + m * EE + tx * 8)     = make_float4(acc[i][0], acc[i][1], acc[i][2], acc[i][3]);
        *(float4*)(pp + m * EE + tx * 8 + 4) = make_float4(acc[i][4], acc[i][5], acc[i][6], acc[i][7]);
    }
}

// ---------------------------------------------------------------------------
// K4: out = sum over splits of partial.  65536 float4 elements.
// ---------------------------------------------------------------------------
__global__ __launch_bounds__(256) void k4_reduce(
    const float* __restrict__ part, float* __restrict__ out)
{
    int idx = blockIdx.x * 256 + threadIdx.x;       // float4 index
    const float4* p = (const float4*)part;
    const int stride = NROWS * EE / 4;              // 65536
    float4 s = p[idx];
    #pragma unroll
    for (int k = 1; k < NSPLIT; k++) {
        float4 t = p[idx + k * stride];
        s.x += t.x; s.y += t.y; s.z += t.z; s.w += t.w;
    }
    ((float4*)out)[idx] = s;
}

extern "C" void kernel_launch(void* const* d_in, const int* in_sizes, int n_in,
                              void* d_out, int out_size, void* d_ws, size_t ws_size,
                              hipStream_t stream) {
    const int*   src  = (const int*)  d_in[0];
    const float* SE   = (const float*)d_in[1];
    const float* W    = (const float*)d_in[2];
    const float* edge = (const float*)d_in[3];
    const int*   rel  = (const int*)  d_in[4];
    float* out  = (float*)d_out;
    float* base = (float*)d_ws;                          // 2048*10000 f32 = 78.1 MiB
    float* part = base + (long long)NROWS * VV;          // 16*2048*128 f32 = 16 MiB

    k1_base_gemm<<<dim3(79, 16), 256, 0, stream>>>(SE, W, base);
    k2_stats<<<dim3(NROWS), 256, 0, stream>>>(src, edge, rel, base);
    k3_gemm<<<dim3(32, NSPLIT), 256, 0, stream>>>(base, W, part);
    k4_reduce<<<dim3(256), 256, 0, stream>>>(part, out);
}